// Round 1
// baseline (177.966 us; speedup 1.0000x reference)
//
#include <hip/hip_runtime.h>
#include <math.h>

#define N_QUBITS 11
#define N_LAYERS 2
#define DIM 2048            // 2^11
#define THREADS 256
#define N_GATES (N_LAYERS * N_QUBITS)   // 22

// One block per batch element. State lives in LDS as split re/im float arrays.
// Gate matrices (22 gates x 2x2 complex) computed once per block by threads 0..21.
__global__ __launch_bounds__(THREADS)
void pqc_sim_kernel(const float* __restrict__ theta,
                    const int* __restrict__ positions,
                    float* __restrict__ out)
{
    __shared__ float sre[DIM];
    __shared__ float sim_[DIM];
    __shared__ float Ure[N_GATES][4];   // [gate][U00,U01,U10,U11] real
    __shared__ float Uim[N_GATES][4];   // imag

    const int b   = blockIdx.x;
    const int tid = threadIdx.x;
    const int pos = positions[b];

    // ---- Precompute gate unitaries: U = Rz(g) * Ry(b) * Rx(a), angles * 0.5 ----
    if (tid < N_GATES) {
        const int l = tid / N_QUBITS;
        const int q = tid % N_QUBITS;
        const float* th = theta + (((size_t)pos * N_LAYERS + l) * (3 * N_QUBITS)) + 3 * q;
        const float a = th[0] * 0.5f;
        const float bb = th[1] * 0.5f;
        const float g = th[2] * 0.5f;
        float sa, ca, sb, cb, sg, cg;
        sincosf(a,  &sa, &ca);
        sincosf(bb, &sb, &cb);
        sincosf(g,  &sg, &cg);
        // M = Ry*Rx:
        //   m00 = cb*ca + i*sb*sa      m01 = -sb*ca - i*cb*sa
        //   m10 = sb*ca - i*cb*sa      m11 =  cb*ca - i*sb*sa
        const float m00r =  cb * ca, m00i =  sb * sa;
        const float m01r = -sb * ca, m01i = -cb * sa;
        const float m10r =  sb * ca, m10i = -cb * sa;
        const float m11r =  cb * ca, m11i = -sb * sa;
        // Row 0 *= e^{-ig} = (cg, -sg); Row 1 *= e^{+ig} = (cg, +sg)
        Ure[tid][0] = m00r * cg + m00i * sg;  Uim[tid][0] = m00i * cg - m00r * sg;
        Ure[tid][1] = m01r * cg + m01i * sg;  Uim[tid][1] = m01i * cg - m01r * sg;
        Ure[tid][2] = m10r * cg - m10i * sg;  Uim[tid][2] = m10i * cg + m10r * sg;
        Ure[tid][3] = m11r * cg - m11i * sg;  Uim[tid][3] = m11i * cg + m11r * sg;
    }

    // ---- Init state |0...0> ----
    for (int i = tid; i < DIM; i += THREADS) {
        sre[i] = 0.0f;
        sim_[i] = 0.0f;
    }
    if (tid == 0) sre[0] = 1.0f;

    // ---- Circuit ----
    for (int l = 0; l < N_LAYERS; ++l) {
        // Single-qubit rotations on qubits 0..10 (pair stride 2^q)
        for (int q = 0; q < N_QUBITS; ++q) {
            __syncthreads();
            const int g = l * N_QUBITS + q;
            const float u00r = Ure[g][0], u00i = Uim[g][0];
            const float u01r = Ure[g][1], u01i = Uim[g][1];
            const float u10r = Ure[g][2], u10i = Uim[g][2];
            const float u11r = Ure[g][3], u11i = Uim[g][3];
            const int mlow = (1 << q) - 1;
            #pragma unroll
            for (int it = 0; it < (DIM / 2) / THREADS; ++it) {
                const int p  = tid + it * THREADS;          // 0..1023
                const int i0 = ((p >> q) << (q + 1)) | (p & mlow);
                const int i1 = i0 | (1 << q);
                const float s0r = sre[i0], s0i = sim_[i0];
                const float s1r = sre[i1], s1i = sim_[i1];
                sre[i0] = u00r * s0r - u00i * s0i + u01r * s1r - u01i * s1i;
                sim_[i0] = u00r * s0i + u00i * s0r + u01r * s1i + u01i * s1r;
                sre[i1] = u10r * s0r - u10i * s0i + u11r * s1r - u11i * s1i;
                sim_[i1] = u10r * s0i + u10i * s0r + u11r * s1i + u11i * s1r;
            }
        }
        // CNOT ladder: control q, target q+1 (swap bit q+1 where bit q == 1)
        for (int q = 0; q < N_QUBITS - 1; ++q) {
            __syncthreads();
            const int mlow = (1 << q) - 1;
            #pragma unroll
            for (int it = 0; it < (DIM / 4) / THREADS; ++it) {
                const int p = tid + it * THREADS;           // 0..511
                // i: bit q = 1, bit q+1 = 0 ; j = i with bit q+1 = 1
                const int i = ((p >> q) << (q + 2)) | (1 << q) | (p & mlow);
                const int j = i | (1 << (q + 1));
                const float tr = sre[i], ti = sim_[i];
                sre[i] = sre[j];  sim_[i] = sim_[j];
                sre[j] = tr;      sim_[j] = ti;
            }
        }
    }

    // ---- Epilogue: real part, coalesced ----
    __syncthreads();
    float* orow = out + (size_t)b * DIM;
    for (int i = tid; i < DIM; i += THREADS) {
        orow[i] = sre[i];
    }
}

extern "C" void kernel_launch(void* const* d_in, const int* in_sizes, int n_in,
                              void* d_out, int out_size, void* d_ws, size_t ws_size,
                              hipStream_t stream)
{
    const float* theta     = (const float*)d_in[0];
    const int*   positions = (const int*)d_in[1];
    float*       out       = (float*)d_out;
    const int B = in_sizes[1];   // 4096 positions -> batch size

    pqc_sim_kernel<<<B, THREADS, 0, stream>>>(theta, positions, out);
}